// Round 5
// baseline (106.580 us; speedup 1.0000x reference)
//
#include <hip/hip_runtime.h>

// QPLayer: per-batch dual QP via 400 fixed PGD iterations.
// Math: q = b (x cancels), M = 2*A*A^T (rank 4), L = 2*||A^T A||_F + 1e-6,
//       alpha = 1/L, lam <- relu(lam - alpha*b - 2*alpha*A(A^T lam)), out = -A^T lam.
// Pre-scale: A' = sqrt(2*alpha)*A  =>  lam <- relu(lam - alpha*b - A'(A'^T lam)),
//       out = -(1/sqrt(2*alpha)) * A'^T lam.
// Decomposition: 4 lanes/problem; lane j owns rows 8j..8j+7 and the matching
// 8 lam entries. Cross-lane: 2-stage DPP quad butterfly. 32768 problems * 4
// lanes = 131072 threads = 2048 waves = 2 waves/SIMD (grid-fixed).
//
// amdgpu_waves_per_eu(1,2): R1/R3/R4 all showed the allocator capping arch
// VGPRs at 32-36 while ~56+ floats are live -> overflow lived in the unified
// file's AGPR side with v_accvgpr_read/write shuttles every use (~98 ghost
// VALU slots/iter = the observed 2.1x gap vs the 88-instr issue model; zero
// scratch traffic ruled out memory spills). __launch_bounds__(256,1) was
// ignored by the allocator; this attribute pins the waves/EU range it budgets
// for. Max=2 matches the grid-supplied occupancy exactly, so the 256-VGPR
// budget is free.

#define QP_ITERS 400

template <int CTRL>
__device__ __forceinline__ float dpp_add(float v) {
    // fused v_add_f32_dpp (old = 0, bound_ctrl = 1)
    return v + __int_as_float(
        __builtin_amdgcn_update_dpp(0, __float_as_int(v), CTRL, 0xF, 0xF, true));
}

__device__ __forceinline__ float quad_sum(float v) {
    v = dpp_add<0xB1>(v);   // quad_perm(1,0,3,2): xor 1
    v = dpp_add<0x4E>(v);   // quad_perm(2,3,0,1): xor 2
    return v;
}

__global__ void __launch_bounds__(256)
__attribute__((amdgpu_waves_per_eu(1, 2)))
qp_pgd_kernel(
        const float* __restrict__ A,   // [nprob, 32, 4]
        const float* __restrict__ b,   // [nprob, 32]
        float* __restrict__ out,       // [nprob, 4]
        int nprob) {
    int t = blockIdx.x * blockDim.x + threadIdx.x;
    int p = t >> 2;          // problem index
    int j = t & 3;           // lane within quad
    if (p >= nprob) return;

    const float4* Ar = reinterpret_cast<const float4*>(A + (size_t)p * 128 + (size_t)j * 32);
    const float4* br = reinterpret_cast<const float4*>(b + (size_t)p * 32 + (size_t)j * 8);

    float ax[8], ay[8], az[8], aw[8];
#pragma unroll
    for (int k = 0; k < 8; ++k) {
        float4 r = Ar[k];
        ax[k] = r.x; ay[k] = r.y; az[k] = r.z; aw[k] = r.w;
    }
    float bb[8];
    {
        float4 b0 = br[0], b1 = br[1];
        bb[0] = b0.x; bb[1] = b0.y; bb[2] = b0.z; bb[3] = b0.w;
        bb[4] = b1.x; bb[5] = b1.y; bb[6] = b1.z; bb[7] = b1.w;
    }

    // ---- alpha = 1 / (2*||A^T A||_F + 1e-6) ----
    float s00 = 0.f, s01 = 0.f, s02 = 0.f, s03 = 0.f;
    float s11 = 0.f, s12 = 0.f, s13 = 0.f;
    float s22 = 0.f, s23 = 0.f, s33 = 0.f;
#pragma unroll
    for (int k = 0; k < 8; ++k) {
        s00 = fmaf(ax[k], ax[k], s00);
        s01 = fmaf(ax[k], ay[k], s01);
        s02 = fmaf(ax[k], az[k], s02);
        s03 = fmaf(ax[k], aw[k], s03);
        s11 = fmaf(ay[k], ay[k], s11);
        s12 = fmaf(ay[k], az[k], s12);
        s13 = fmaf(ay[k], aw[k], s13);
        s22 = fmaf(az[k], az[k], s22);
        s23 = fmaf(az[k], aw[k], s23);
        s33 = fmaf(aw[k], aw[k], s33);
    }
    s00 = quad_sum(s00); s01 = quad_sum(s01); s02 = quad_sum(s02); s03 = quad_sum(s03);
    s11 = quad_sum(s11); s12 = quad_sum(s12); s13 = quad_sum(s13);
    s22 = quad_sum(s22); s23 = quad_sum(s23); s33 = quad_sum(s33);
    float ssq = s00 * s00 + s11 * s11 + s22 * s22 + s33 * s33
              + 2.f * (s01 * s01 + s02 * s02 + s03 * s03
                     + s12 * s12 + s13 * s13 + s23 * s23);
    float L = 2.f * sqrtf(ssq) + 1e-6f;
    float alpha = 1.f / L;
    float sc = sqrtf(2.f * alpha);     // A' = sc * A
    float inv_sc = 1.f / sc;

#pragma unroll
    for (int k = 0; k < 8; ++k) {
        ax[k] *= sc; ay[k] *= sc; az[k] *= sc; aw[k] *= sc;
    }
    float c[8];
#pragma unroll
    for (int k = 0; k < 8; ++k) c[k] = alpha * bb[k];

    // ---- 400 PGD iterations ----
    float lam[8];
#pragma unroll
    for (int k = 0; k < 8; ++k) lam[k] = 0.f;

    for (int it = 0; it < QP_ITERS; ++it) {
        // partial u' = A'^T lam over this lane's 8 rows (4 independent FMA chains)
        float u0 = 0.f, u1 = 0.f, u2 = 0.f, u3 = 0.f;
#pragma unroll
        for (int k = 0; k < 8; ++k) {
            u0 = fmaf(ax[k], lam[k], u0);
            u1 = fmaf(ay[k], lam[k], u1);
            u2 = fmaf(az[k], lam[k], u2);
            u3 = fmaf(aw[k], lam[k], u3);
        }
        u0 = quad_sum(u0); u1 = quad_sum(u1); u2 = quad_sum(u2); u3 = quad_sum(u3);
        // lam[m] = relu(lam[m] - alpha*b[m] - A'[m]·u')
#pragma unroll
        for (int k = 0; k < 8; ++k) {
            float tt = lam[k] - c[k];
            tt = fmaf(ax[k], -u0, tt);
            tt = fmaf(ay[k], -u1, tt);
            tt = fmaf(az[k], -u2, tt);
            tt = fmaf(aw[k], -u3, tt);
            lam[k] = fmaxf(tt, 0.f);
        }
    }

    // ---- output: out = -A^T lam = -(1/sc) * A'^T lam ----
    float u0 = 0.f, u1 = 0.f, u2 = 0.f, u3 = 0.f;
#pragma unroll
    for (int k = 0; k < 8; ++k) {
        u0 = fmaf(ax[k], lam[k], u0);
        u1 = fmaf(ay[k], lam[k], u1);
        u2 = fmaf(az[k], lam[k], u2);
        u3 = fmaf(aw[k], lam[k], u3);
    }
    u0 = quad_sum(u0); u1 = quad_sum(u1); u2 = quad_sum(u2); u3 = quad_sum(u3);
    float r = (j & 1) ? ((j & 2) ? u3 : u1) : ((j & 2) ? u2 : u0);
    out[(size_t)p * 4 + j] = -r * inv_sc;
}

extern "C" void kernel_launch(void* const* d_in, const int* in_sizes, int n_in,
                              void* d_out, int out_size, void* d_ws, size_t ws_size,
                              hipStream_t stream) {
    const float* A = (const float*)d_in[0];
    // d_in[1] (x) cancels analytically and is unused.
    const float* b = (const float*)d_in[2];
    float* out = (float*)d_out;

    int nprob = in_sizes[2] / 32;          // B = 32768
    int threads = nprob * 4;               // 4 lanes per problem
    dim3 block(256);
    dim3 grid((threads + 255) / 256);
    hipLaunchKernelGGL(qp_pgd_kernel, grid, block, 0, stream, A, b, out, nprob);
}